// Round 1
// baseline (1724.369 us; speedup 1.0000x reference)
//
#include <hip/hip_runtime.h>
#include <hip/hip_bf16.h>
#include <math.h>

#define B 4
#define C 128
#define HW 196          // 14*14
#define P 2000
#define NCLS 200
#define OUT 224
#define EPS 1e-4f

// ---------------------------------------------------------------------------
// Kernel 1: add_on_layers. f = sigmoid(W2 * relu(W1 * fmap + b1) + b2)
// One block = 256 threads = 2 pixels x 128 output channels.
// ---------------------------------------------------------------------------
__global__ __launch_bounds__(256) void addon_kernel(
    const float* __restrict__ fmap, const float* __restrict__ w1,
    const float* __restrict__ b1,   const float* __restrict__ w2,
    const float* __restrict__ b2,   float* __restrict__ f)
{
    int tid   = threadIdx.x;
    int o     = tid & 127;          // output channel
    int which = tid >> 7;           // 0/1: pixel within block
    int pix   = blockIdx.x * 2 + which;   // 0..783
    int b     = pix / HW;
    int hw    = pix - b * HW;

    __shared__ float inbuf[2][C];
    __shared__ float hbuf[2][C];

    // stage input pixel channel-vector
    inbuf[which][o] = fmap[(b * C + o) * HW + hw];
    __syncthreads();

    float acc = b1[o];
    const float* wr = w1 + o * C;
#pragma unroll 8
    for (int c = 0; c < C; ++c) acc = fmaf(inbuf[which][c], wr[c], acc);
    hbuf[which][o] = fmaxf(acc, 0.0f);
    __syncthreads();

    float acc2 = b2[o];
    const float* wr2 = w2 + o * C;
#pragma unroll 8
    for (int c = 0; c < C; ++c) acc2 = fmaf(hbuf[which][c], wr2[c], acc2);
    float fv = 1.0f / (1.0f + expf(-acc2));
    f[(b * C + o) * HW + hw] = fv;
}

// ---------------------------------------------------------------------------
// Kernel 2: per-(b,p) plane: L2 distance at 14x14, bilinear x16 upsample to
// 224x224 (write to d_out), global min -> min_distances.
// grid = (P, B), block = 256.
// ---------------------------------------------------------------------------
__global__ __launch_bounds__(256) void dist_up_kernel(
    const float* __restrict__ f,       // (B,C,196)
    const float* __restrict__ protos,  // (P,C)
    float* __restrict__ up,            // (B,P,224,224)
    float* __restrict__ min_d)         // (B,P)
{
    int p = blockIdx.x;
    int b = blockIdx.y;
    int tid = threadIdx.x;

    __shared__ float d[HW];            // 14x14 distances
    __shared__ float rowi[14 * OUT];   // horizontally interpolated rows
    __shared__ float red[4];

    // --- distances (196 active threads) ---
    if (tid < HW) {
        const float* fb = f + b * C * HW + tid;
        const float* pp = protos + p * C;
        float cross = 0.f, f2 = 0.f, p2 = 0.f;
#pragma unroll 8
        for (int c = 0; c < C; ++c) {
            float fv = fb[c * HW];
            float pv = pp[c];
            cross = fmaf(fv, pv, cross);
            f2    = fmaf(fv, fv, f2);
            p2    = fmaf(pv, pv, p2);
        }
        float d2 = fmaxf(f2 + p2 - 2.0f * cross, 0.0f);
        d[tid] = sqrtf(d2 + 1e-12f);
    }
    __syncthreads();

    // --- horizontal interpolation: rowi[y][i], y in [0,14), i in [0,224) ---
    for (int v = tid; v < 14 * OUT; v += 256) {
        int y = v / OUT;
        int i = v - y * OUT;
        float fx  = (i + 0.5f) * 0.0625f - 0.5f;   // half-pixel, scale 1/16
        float x0f = floorf(fx);
        float wx  = fx - x0f;
        int x0 = (int)x0f;
        int x1 = x0 + 1;
        x0 = max(0, min(13, x0));
        x1 = max(0, min(13, x1));
        float v0 = d[y * 14 + x0];
        float v1 = d[y * 14 + x1];
        rowi[v] = fmaf(wx, v1 - v0, v0);
    }
    __syncthreads();

    // --- vertical interpolation + streaming store + min ---
    float* outp = up + (size_t)(b * P + p) * (OUT * OUT);
    float vmin = INFINITY;
    // 224*224/4 = 12544 float4 = 256 threads * 49 iters exactly
    for (int q = tid; q < (OUT * OUT / 4); q += 256) {
        int j = q / (OUT / 4);              // output row
        int k = q - j * (OUT / 4);          // float4 column index
        float fy  = (j + 0.5f) * 0.0625f - 0.5f;
        float y0f = floorf(fy);
        float wy  = fy - y0f;
        int y0 = (int)y0f;
        int y1 = y0 + 1;
        y0 = max(0, min(13, y0));
        y1 = max(0, min(13, y1));
        const float4 a  = *(const float4*)&rowi[y0 * OUT + k * 4];
        const float4 c4 = *(const float4*)&rowi[y1 * OUT + k * 4];
        float4 o;
        o.x = fmaf(wy, c4.x - a.x, a.x);
        o.y = fmaf(wy, c4.y - a.y, a.y);
        o.z = fmaf(wy, c4.z - a.z, a.z);
        o.w = fmaf(wy, c4.w - a.w, a.w);
        ((float4*)outp)[q] = o;
        vmin = fminf(vmin, fminf(fminf(o.x, o.y), fminf(o.z, o.w)));
    }

    // --- block min reduction ---
#pragma unroll
    for (int off = 32; off > 0; off >>= 1)
        vmin = fminf(vmin, __shfl_down(vmin, off, 64));
    if ((tid & 63) == 0) red[tid >> 6] = vmin;
    __syncthreads();
    if (tid == 0) {
        float m = fminf(fminf(red[0], red[1]), fminf(red[2], red[3]));
        min_d[b * P + p] = m;
    }
}

// ---------------------------------------------------------------------------
// Kernel 3: acts = log((m+1)/(m+EPS)); logits = acts @ last_w^T
// grid = B, block = 256.
// ---------------------------------------------------------------------------
__global__ __launch_bounds__(256) void head_kernel(
    const float* __restrict__ min_d,   // (B,P)
    const float* __restrict__ last_w,  // (NCLS,P)
    float* __restrict__ logits)        // (B,NCLS)
{
    int b = blockIdx.x;
    int tid = threadIdx.x;
    __shared__ float acts[P];
    for (int p = tid; p < P; p += 256) {
        float m = min_d[b * P + p];
        acts[p] = logf((m + 1.0f) / (m + EPS));
    }
    __syncthreads();
    if (tid < NCLS) {
        const float* wr = last_w + tid * P;
        float acc = 0.f;
#pragma unroll 4
        for (int p = 0; p < P; ++p) acc = fmaf(acts[p], wr[p], acc);
        logits[b * NCLS + tid] = acc;
    }
}

// ---------------------------------------------------------------------------
extern "C" void kernel_launch(void* const* d_in, const int* in_sizes, int n_in,
                              void* d_out, int out_size, void* d_ws, size_t ws_size,
                              hipStream_t stream)
{
    const float* fmap   = (const float*)d_in[0];
    const float* w1     = (const float*)d_in[1];
    const float* b1     = (const float*)d_in[2];
    const float* w2     = (const float*)d_in[3];
    const float* b2     = (const float*)d_in[4];
    const float* protos = (const float*)d_in[5];
    const float* last_w = (const float*)d_in[6];

    float* out    = (float*)d_out;
    float* logits = out;                      // (B,NCLS)        = 800
    float* min_d  = out + B * NCLS;           // (B,P)           = 8000
    float* up     = out + B * NCLS + B * P;   // (B,P,224,224)

    float* f = (float*)d_ws;                  // (B,C,196) = 401408 bytes

    addon_kernel<<<dim3(B * HW / 2), dim3(256), 0, stream>>>(fmap, w1, b1, w2, b2, f);
    dist_up_kernel<<<dim3(P, B), dim3(256), 0, stream>>>(f, protos, up, min_d);
    head_kernel<<<dim3(B), dim3(256), 0, stream>>>(min_d, last_w, logits);
}